// Round 1
// baseline (901.177 us; speedup 1.0000x reference)
//
#include <hip/hip_runtime.h>

#define NPTS 100000
#define KN 16
#define DIM 3
#define CIN 64
#define CD 16
#define CT 80
#define COUT 128
#define PTS 4
#define EPSV 1e-5f

__device__ __forceinline__ float sgnf(float x) {
    return (x > 0.f) ? 1.f : ((x < 0.f) ? -1.f : 0.f);
}
__device__ __forceinline__ float clamp1(float x) {
    return fminf(1.f, fmaxf(-1.f, x));
}

__global__ __launch_bounds__(256) void bixconv_kernel(
    const float* __restrict__ x, const float* __restrict__ pos, const int* __restrict__ col,
    const float* __restrict__ W1, const float* __restrict__ b1,
    const float* __restrict__ bn1g, const float* __restrict__ bn1b, const float* __restrict__ bn1m, const float* __restrict__ bn1v,
    const float* __restrict__ W2, const float* __restrict__ b2,
    const float* __restrict__ bn2g, const float* __restrict__ bn2b, const float* __restrict__ bn2m, const float* __restrict__ bn2v,
    const float* __restrict__ Wm, const float* __restrict__ bm,
    const float* __restrict__ bn3g, const float* __restrict__ bn3b, const float* __restrict__ bn3m, const float* __restrict__ bn3v,
    const float* __restrict__ cw1, const float* __restrict__ cb1,
    const float* __restrict__ bn4g, const float* __restrict__ bn4b, const float* __restrict__ bn4m, const float* __restrict__ bn4v,
    const float* __restrict__ cw2, const float* __restrict__ cb2,
    const float* __restrict__ bn5g, const float* __restrict__ bn5b, const float* __restrict__ bn5m, const float* __restrict__ bn5v,
    const float* __restrict__ cw3, const float* __restrict__ cb3,
    const float* __restrict__ Wf, const float* __restrict__ bf,
    float* __restrict__ out)
{
    __shared__ int   sIdx[PTS][KN];
    __shared__ float sPd[PTS][KN * DIM];       // pd flattened k*3+d
    __shared__ float sXs[PTS][CT][KN + 1];     // xs (c,k); later rows hold sign(xt)
    __shared__ float sT[PTS][KN][KN + 1];      // h1 first, then T
    __shared__ float sS1[PTS][256];            // sign(t1); later sign(y) in [0..159]
    __shared__ float sS2[PTS][256];            // sign(t2)

    const int tid = threadIdx.x;
    const int nb = blockIdx.x * PTS;

    // ---- A1: neighbor indices + relative positions ----
    if (tid < PTS * KN) {
        int p = tid >> 4, k = tid & 15;
        int n = nb + p;
        int idx = col[n * KN + k];
        sIdx[p][k] = idx;
        float ax = pos[n * 3 + 0], ay = pos[n * 3 + 1], az = pos[n * 3 + 2];
        sPd[p][k * 3 + 0] = pos[idx * 3 + 0] - ax;
        sPd[p][k * 3 + 1] = pos[idx * 3 + 1] - ay;
        sPd[p][k * 3 + 2] = pos[idx * 3 + 2] - az;
    }
    __syncthreads();

    // ---- A2: gather x[col] into xs rows 16..79 ----
    {
        int c = tid & 63, p = tid >> 6;
        for (int k = 0; k < KN; ++k) {
            int idx = sIdx[p][k];
            sXs[p][CD + c][k] = x[(size_t)idx * CIN + c];
        }
    }
    // ---- B: h1 = bn1(hardtanh(pd @ W1^T + b1)) -> sT ----
    {
        int c = tid & 15, k = tid >> 4;
        float w0 = W1[c * 3 + 0], w1 = W1[c * 3 + 1], w2 = W1[c * 3 + 2];
        float bb = b1[c];
        float s = bn1g[c] * rsqrtf(bn1v[c] + EPSV);
        float t = bn1b[c] - bn1m[c] * s;
        #pragma unroll
        for (int p = 0; p < PTS; ++p) {
            float z = sPd[p][k * 3 + 0] * w0 + sPd[p][k * 3 + 1] * w1 + sPd[p][k * 3 + 2] * w2 + bb;
            sT[p][k][c] = clamp1(z) * s + t;
        }
    }
    __syncthreads();

    // ---- C: h2 = bn2(hardtanh(sign(h1) @ sign(W2)^T + b2)) -> xs rows 0..15 ----
    {
        int c = tid & 15, k = tid >> 4;
        float wsg[16];
        #pragma unroll
        for (int j = 0; j < 16; ++j) wsg[j] = sgnf(W2[c * 16 + j]);
        float bb = b2[c];
        float s = bn2g[c] * rsqrtf(bn2v[c] + EPSV);
        float t = bn2b[c] - bn2m[c] * s;
        #pragma unroll
        for (int p = 0; p < PTS; ++p) {
            float acc = bb;
            #pragma unroll
            for (int j = 0; j < 16; ++j) acc += sgnf(sT[p][k][j]) * wsg[j];
            sXs[p][c][k] = clamp1(acc) * s + t;
        }
    }
    // ---- D: t1 = sign(bn3(hardtanh(pdf @ Wm^T + bm))) -> sS1 ----
    {
        int j = tid; // 0..255
        float bb = bm[j];
        float s = bn3g[j] * rsqrtf(bn3v[j] + EPSV);
        float t = bn3b[j] - bn3m[j] * s;
        float acc[PTS] = {0.f, 0.f, 0.f, 0.f};
        for (int i = 0; i < KN * DIM; ++i) {
            float w = Wm[j * (KN * DIM) + i];
            #pragma unroll
            for (int p = 0; p < PTS; ++p) acc[p] += w * sPd[p][i];
        }
        #pragma unroll
        for (int p = 0; p < PTS; ++p)
            sS1[p][j] = sgnf(clamp1(acc[p] + bb) * s + t);
    }
    __syncthreads();

    // ---- E: t2 = sign(bn4(hardtanh(bigconv(t1, cw1) + cb1))) -> sS2 ----
    {
        int r = tid; int c = r >> 4;
        float wsg[16];
        #pragma unroll
        for (int k = 0; k < 16; ++k) wsg[k] = sgnf(cw1[r * 16 + k]);
        float bb = cb1[r];
        float s = bn4g[r] * rsqrtf(bn4v[r] + EPSV);
        float t = bn4b[r] - bn4m[r] * s;
        #pragma unroll
        for (int p = 0; p < PTS; ++p) {
            float acc = bb;
            #pragma unroll
            for (int k = 0; k < 16; ++k) acc += sS1[p][c * 16 + k] * wsg[k];
            sS2[p][r] = sgnf(clamp1(acc) * s + t);
        }
    }
    __syncthreads();

    // ---- F: T = bn5(bigconv(t2, cw2) + cb2) (no hardtanh) -> sT ----
    {
        int r = tid; int i = r >> 4, jj = r & 15;
        float wsg[16];
        #pragma unroll
        for (int k = 0; k < 16; ++k) wsg[k] = sgnf(cw2[r * 16 + k]);
        float bb = cb2[r];
        float s = bn5g[r] * rsqrtf(bn5v[r] + EPSV);
        float t = bn5b[r] - bn5m[r] * s;
        #pragma unroll
        for (int p = 0; p < PTS; ++p) {
            float acc = bb;
            #pragma unroll
            for (int k = 0; k < 16; ++k) acc += sS2[p][i * 16 + k] * wsg[k];
            sT[p][i][jj] = acc * s + t;
        }
    }
    __syncthreads();

    // ---- G: xt[c][i] = sum_j T[i][j]*xs[c][j]; store sign(xt) in place ----
    {
        int p = tid >> 6, l = tid & 63;
        #pragma unroll
        for (int pass = 0; pass < 2; ++pass) {
            int c = (pass == 0) ? l : 64 + l;
            if (c < CT) {
                float r[16];
                #pragma unroll
                for (int j = 0; j < 16; ++j) r[j] = sXs[p][c][j];
                float o[16];
                #pragma unroll
                for (int i = 0; i < 16; ++i) {
                    float acc = 0.f;
                    #pragma unroll
                    for (int j = 0; j < 16; ++j) acc += sT[p][i][j] * r[j];
                    o[i] = sgnf(acc);
                }
                #pragma unroll
                for (int i = 0; i < 16; ++i) sXs[p][c][i] = o[i];
            }
        }
    }
    __syncthreads();

    // ---- H: y = bigconv(sign(xt), cw3) + cb3; store sign(y) -> sS1[0..159] ----
    if (tid < CT * 2) {
        int q = tid; int c = q >> 1;
        float wsg[16];
        #pragma unroll
        for (int k = 0; k < 16; ++k) wsg[k] = sgnf(cw3[q * 16 + k]);
        float bb = cb3[q];
        #pragma unroll
        for (int p = 0; p < PTS; ++p) {
            float acc = bb;
            #pragma unroll
            for (int k = 0; k < 16; ++k) acc += sXs[p][c][k] * wsg[k];
            sS1[p][q] = sgnf(acc);
        }
    }
    __syncthreads();

    // ---- I: out = sign(y) @ sign(Wf)^T + bf ----
    {
        int o = tid & 127, pp = tid >> 7; // pp=0 -> points 0,1 ; pp=1 -> points 2,3
        float bb = bf[o];
        float acc0 = 0.f, acc1 = 0.f;
        for (int q = 0; q < CT * 2; ++q) {
            float w = sgnf(Wf[o * (CT * 2) + q]);
            acc0 += sS1[2 * pp + 0][q] * w;
            acc1 += sS1[2 * pp + 1][q] * w;
        }
        out[(size_t)(nb + 2 * pp + 0) * COUT + o] = acc0 + bb;
        out[(size_t)(nb + 2 * pp + 1) * COUT + o] = acc1 + bb;
    }
}

extern "C" void kernel_launch(void* const* d_in, const int* in_sizes, int n_in,
                              void* d_out, int out_size, void* d_ws, size_t ws_size,
                              hipStream_t stream) {
    const float* x    = (const float*)d_in[0];
    const float* pos  = (const float*)d_in[1];
    const int*   col  = (const int*)d_in[2];
    const float* W1   = (const float*)d_in[3];
    const float* b1   = (const float*)d_in[4];
    const float* bn1g = (const float*)d_in[5];
    const float* bn1b = (const float*)d_in[6];
    const float* bn1m = (const float*)d_in[7];
    const float* bn1v = (const float*)d_in[8];
    const float* W2   = (const float*)d_in[9];
    const float* b2   = (const float*)d_in[10];
    const float* bn2g = (const float*)d_in[11];
    const float* bn2b = (const float*)d_in[12];
    const float* bn2m = (const float*)d_in[13];
    const float* bn2v = (const float*)d_in[14];
    const float* Wm   = (const float*)d_in[15];
    const float* bm   = (const float*)d_in[16];
    const float* bn3g = (const float*)d_in[17];
    const float* bn3b = (const float*)d_in[18];
    const float* bn3m = (const float*)d_in[19];
    const float* bn3v = (const float*)d_in[20];
    const float* cw1  = (const float*)d_in[21];
    const float* cb1  = (const float*)d_in[22];
    const float* bn4g = (const float*)d_in[23];
    const float* bn4b = (const float*)d_in[24];
    const float* bn4m = (const float*)d_in[25];
    const float* bn4v = (const float*)d_in[26];
    const float* cw2  = (const float*)d_in[27];
    const float* cb2  = (const float*)d_in[28];
    const float* bn5g = (const float*)d_in[29];
    const float* bn5b = (const float*)d_in[30];
    const float* bn5m = (const float*)d_in[31];
    const float* bn5v = (const float*)d_in[32];
    const float* cw3  = (const float*)d_in[33];
    const float* cb3  = (const float*)d_in[34];
    const float* Wf   = (const float*)d_in[35];
    const float* bf   = (const float*)d_in[36];
    float* outp = (float*)d_out;

    dim3 grid(NPTS / PTS), block(256);
    hipLaunchKernelGGL(bixconv_kernel, grid, block, 0, stream,
        x, pos, col,
        W1, b1, bn1g, bn1b, bn1m, bn1v,
        W2, b2, bn2g, bn2b, bn2m, bn2v,
        Wm, bm, bn3g, bn3b, bn3m, bn3v,
        cw1, cb1, bn4g, bn4b, bn4m, bn4v,
        cw2, cb2, bn5g, bn5b, bn5m, bn5v,
        cw3, cb3, Wf, bf, outp);
}

// Round 3
// 409.173 us; speedup vs baseline: 2.2024x; 2.2024x over previous
//
#include <hip/hip_runtime.h>

#define NPTS 100000
#define KN 16
#define DIM 3
#define CIN 64
#define CD 16
#define CT 80
#define COUT 128
#define PTS 4
#define EPSV 1e-5f

// ---- prepacked weights (written by prep_kernel every launch; deterministic) ----
__device__ float    g_wmt2[48 * 256];   // [i*256 + j] = Wm[j*48 + i]  (coalesced over j)
__device__ unsigned g_w2[2][16];
__device__ unsigned g_cw1[2][256];
__device__ unsigned g_cw2[2][256];
__device__ unsigned g_cw3[2][160];
__device__ unsigned g_wf[2][1280];      // Wf row o -> 10 words

__device__ __forceinline__ float sgnf(float x) {
    return (x > 0.f) ? 1.f : ((x < 0.f) ? -1.f : 0.f);
}
__device__ __forceinline__ float clamp1(float x) { return fminf(1.f, fmaxf(-1.f, x)); }
__device__ __forceinline__ unsigned rot16(unsigned w) { return (w >> 16) | (w << 16); }

__device__ __forceinline__ unsigned packrow16(const float* __restrict__ w) {
    unsigned pos = 0, neg = 0;
    #pragma unroll
    for (int k = 0; k < 16; ++k) {
        pos |= (w[k] > 0.f ? 1u : 0u) << k;
        neg |= (w[k] < 0.f ? 1u : 0u) << k;
    }
    return (neg << 16) | pos;
}

// sign float {-1,0,1} from packed word bit k
__device__ __forceinline__ float bit_sgn(unsigned w, int k) {
    return (float)((w >> k) & 1u) - (float)((w >> (k + 16)) & 1u);
}

// ternary dot of 16-elem packed words: a=(an<<16)|ap, wp=(wn<<16)|wpos, wr=rot16(wp)
__device__ __forceinline__ int tdot(unsigned a, unsigned wp, unsigned wr) {
    return __popc(a & wp) - __popc(a & wr);
}

__global__ void prep_kernel(const float* __restrict__ Wm, const float* __restrict__ W2,
                            const float* __restrict__ cw1, const float* __restrict__ cw2,
                            const float* __restrict__ cw3, const float* __restrict__ Wf) {
    int b = blockIdx.x, t = threadIdx.x;
    if (b < 48) {
        g_wmt2[b * 256 + t] = Wm[t * 48 + b];
    } else if (b == 48) {
        unsigned w = packrow16(cw1 + t * 16);
        g_cw1[0][t] = w; g_cw1[1][t] = rot16(w);
    } else if (b == 49) {
        unsigned w = packrow16(cw2 + t * 16);
        g_cw2[0][t] = w; g_cw2[1][t] = rot16(w);
    } else if (b == 50) {
        if (t < 160) { unsigned w = packrow16(cw3 + t * 16); g_cw3[0][t] = w; g_cw3[1][t] = rot16(w); }
        else if (t < 176) { int c = t - 160; unsigned w = packrow16(W2 + c * 16); g_w2[0][c] = w; g_w2[1][c] = rot16(w); }
    } else {
        if (t < 128) {
            for (int m = 0; m < 10; ++m) {
                unsigned w = packrow16(Wf + t * 160 + m * 16);
                g_wf[0][t * 10 + m] = w; g_wf[1][t * 10 + m] = rot16(w);
            }
        }
    }
}

__global__ __launch_bounds__(256) void bixconv_kernel(
    const float* __restrict__ x, const float* __restrict__ pos, const int* __restrict__ col,
    const float* __restrict__ W1, const float* __restrict__ b1,
    const float* __restrict__ bn1g, const float* __restrict__ bn1b, const float* __restrict__ bn1m, const float* __restrict__ bn1v,
    const float* __restrict__ b2,
    const float* __restrict__ bn2g, const float* __restrict__ bn2b, const float* __restrict__ bn2m, const float* __restrict__ bn2v,
    const float* __restrict__ bm,
    const float* __restrict__ bn3g, const float* __restrict__ bn3b, const float* __restrict__ bn3m, const float* __restrict__ bn3v,
    const float* __restrict__ cb1,
    const float* __restrict__ bn4g, const float* __restrict__ bn4b, const float* __restrict__ bn4m, const float* __restrict__ bn4v,
    const float* __restrict__ cb2,
    const float* __restrict__ bn5g, const float* __restrict__ bn5b, const float* __restrict__ bn5m, const float* __restrict__ bn5v,
    const float* __restrict__ cb3, const float* __restrict__ bf,
    float* __restrict__ out)
{
    __shared__ int sIdx[PTS][KN];
    __shared__ __align__(16) float sPd[PTS][48];
    __shared__ __align__(16) float sXs[PTS][CT][20];   // rows 0..15: h2, rows 16..79: x[col]
    __shared__ __align__(16) float sT[PTS][KN][20];    // h1 first, then T
    __shared__ float sS1[PTS][256];                    // sign(t1) floats; later sign(y) floats [0..159]
    __shared__ float sS2[PTS][256];                    // sign(t2) floats
    __shared__ unsigned sPkXt[PTS][CT];                // packed sign(xt)
    __shared__ unsigned sPkY[PTS][10];                 // packed sign(y)

    const int tid = threadIdx.x;
    const int lane = tid & 63;
    const int nb = blockIdx.x * PTS;

    // ---- A1: neighbor indices + relative positions ----
    if (tid < PTS * KN) {
        int p = tid >> 4, k = tid & 15;
        int n = nb + p;
        int idx = col[n * KN + k];
        sIdx[p][k] = idx;
        float ax = pos[n * 3 + 0], ay = pos[n * 3 + 1], az = pos[n * 3 + 2];
        sPd[p][k * 3 + 0] = pos[idx * 3 + 0] - ax;
        sPd[p][k * 3 + 1] = pos[idx * 3 + 1] - ay;
        sPd[p][k * 3 + 2] = pos[idx * 3 + 2] - az;
    }
    __syncthreads();

    // ---- A2: gather x[col] into xs rows 16..79 (float4 LDS stores; values identical to scalar) ----
    {
        int p = tid >> 6, c = lane;
        #pragma unroll
        for (int kb = 0; kb < 4; ++kb) {
            float4 v;
            v.x = x[(size_t)sIdx[p][kb * 4 + 0] * CIN + c];
            v.y = x[(size_t)sIdx[p][kb * 4 + 1] * CIN + c];
            v.z = x[(size_t)sIdx[p][kb * 4 + 2] * CIN + c];
            v.w = x[(size_t)sIdx[p][kb * 4 + 3] * CIN + c];
            *(float4*)&sXs[p][CD + c][kb * 4] = v;
        }
    }
    // ---- B: h1 = bn1(hardtanh(pd @ W1^T + b1)) -> sT (round-1 exact) ----
    {
        int c = tid & 15, k = tid >> 4;
        float w0 = W1[c * 3 + 0], w1 = W1[c * 3 + 1], w2v = W1[c * 3 + 2];
        float bb = b1[c];
        float s = bn1g[c] * rsqrtf(bn1v[c] + EPSV);
        float tt = bn1b[c] - bn1m[c] * s;
        #pragma unroll
        for (int p = 0; p < PTS; ++p) {
            float z = sPd[p][k * 3 + 0] * w0 + sPd[p][k * 3 + 1] * w1 + sPd[p][k * 3 + 2] * w2v + bb;
            sT[p][k][c] = clamp1(z) * s + tt;
        }
    }
    __syncthreads();

    // ---- C: h2 = bn2(hardtanh(sign(h1) . sign(W2))) -> sXs rows 0..15 (round-1 exact order) ----
    {
        int c = tid & 15, k = tid >> 4;
        unsigned wpk = g_w2[0][c];
        float wsg[16];
        #pragma unroll
        for (int j = 0; j < 16; ++j) wsg[j] = bit_sgn(wpk, j);
        float bb = b2[c];
        float s = bn2g[c] * rsqrtf(bn2v[c] + EPSV);
        float tt = bn2b[c] - bn2m[c] * s;
        #pragma unroll
        for (int p = 0; p < PTS; ++p) {
            float acc = bb;
            #pragma unroll
            for (int j = 0; j < 16; ++j) acc += sgnf(sT[p][k][j]) * wsg[j];
            sXs[p][c][k] = clamp1(acc) * s + tt;
        }
    }
    // ---- D: t1 = sign(bn3(hardtanh(pd48 @ Wm^T + bm))) -> sS1 floats (round-1 order, coalesced weights) ----
    {
        int j = tid;
        float acc[PTS] = {0.f, 0.f, 0.f, 0.f};
        for (int i = 0; i < KN * DIM; ++i) {
            float w = g_wmt2[i * 256 + j];
            #pragma unroll
            for (int p = 0; p < PTS; ++p) acc[p] += w * sPd[p][i];
        }
        float bb = bm[j];
        float s = bn3g[j] * rsqrtf(bn3v[j] + EPSV);
        float tt = bn3b[j] - bn3m[j] * s;
        #pragma unroll
        for (int p = 0; p < PTS; ++p)
            sS1[p][j] = sgnf(clamp1(acc[p] + bb) * s + tt);
    }
    __syncthreads();

    // ---- E: t2 = sign(bn4(hardtanh(bigconv(t1, cw1)))) -> sS2 floats (round-1 exact order) ----
    {
        int r = tid, c = r >> 4;
        unsigned wpk = g_cw1[0][r];
        float wsg[16];
        #pragma unroll
        for (int k = 0; k < 16; ++k) wsg[k] = bit_sgn(wpk, k);
        float bb = cb1[r];
        float s = bn4g[r] * rsqrtf(bn4v[r] + EPSV);
        float tt = bn4b[r] - bn4m[r] * s;
        #pragma unroll
        for (int p = 0; p < PTS; ++p) {
            float acc = bb;
            #pragma unroll
            for (int k = 0; k < 16; ++k) acc += sS1[p][c * 16 + k] * wsg[k];
            sS2[p][r] = sgnf(clamp1(acc) * s + tt);
        }
    }
    __syncthreads();

    // ---- F: T = bn5(bigconv(t2, cw2)) (no hardtanh) -> sT (round-1 exact order) ----
    {
        int r = tid, c = r >> 4;
        unsigned wpk = g_cw2[0][r];
        float wsg[16];
        #pragma unroll
        for (int k = 0; k < 16; ++k) wsg[k] = bit_sgn(wpk, k);
        float bb = cb2[r];
        float s = bn5g[r] * rsqrtf(bn5v[r] + EPSV);
        float tt = bn5b[r] - bn5m[r] * s;
        int i = r >> 4, jj = r & 15;
        #pragma unroll
        for (int p = 0; p < PTS; ++p) {
            float acc = bb;
            #pragma unroll
            for (int k = 0; k < 16; ++k) acc += sS2[p][c * 16 + k] * wsg[k];
            sT[p][i][jj] = acc * s + tt;
        }
    }
    __syncthreads();

    // ---- G: xt[c][i] = sum_j T[i][j]*xs[c][j] (round-1 exact order); pack signs -> sPkXt ----
    {
        int p = tid >> 6, c0 = lane;
        #pragma unroll
        for (int pass = 0; pass < 2; ++pass) {
            int c = c0 + pass * 64;
            if (c < CT) {
                float r[16];
                #pragma unroll
                for (int j = 0; j < 16; ++j) r[j] = sXs[p][c][j];
                unsigned pw = 0;
                #pragma unroll
                for (int i = 0; i < 16; ++i) {
                    float acc = 0.f;
                    #pragma unroll
                    for (int j = 0; j < 16; ++j) acc += sT[p][i][j] * r[j];
                    pw |= (acc > 0.f ? 1u : 0u) << i;
                    pw |= (acc < 0.f ? 1u : 0u) << (16 + i);
                }
                sPkXt[p][c] = pw;
            }
        }
    }
    __syncthreads();

    // ---- H: y = bigconv(sign(xt), cw3) + cb3; sign(y) floats -> sS1[0..159] ----
    if (tid < CT * 2) {
        int q = tid, c = q >> 1;
        unsigned wp = g_cw3[0][q], wr = g_cw3[1][q];
        float bb = cb3[q];
        #pragma unroll
        for (int p = 0; p < PTS; ++p) {
            unsigned a = sPkXt[p][c];
            float v = (float)tdot(a, wp, wr) + bb;
            sS1[p][q] = sgnf(v);
        }
    }
    __syncthreads();

    // ---- pack sign(y) -> sPkY ----
    if (tid < PTS * 10) {
        int p = tid / 10, m = tid % 10;
        unsigned w = 0;
        #pragma unroll
        for (int k = 0; k < 16; ++k) {
            float v = sS1[p][m * 16 + k];
            w |= (v > 0.f ? 1u : 0u) << k;
            w |= (v < 0.f ? 1u : 0u) << (16 + k);
        }
        sPkY[p][m] = w;
    }
    __syncthreads();

    // ---- I: out = sign(y) . sign(Wf) + bf (packed; integer-exact == round-1) ----
    {
        int o = tid & 127, pp = tid >> 7;
        float bb = bf[o];
        unsigned a0[10], a1[10];
        #pragma unroll
        for (int m = 0; m < 10; ++m) { a0[m] = sPkY[2 * pp][m]; a1[m] = sPkY[2 * pp + 1][m]; }
        int acc0 = 0, acc1 = 0;
        #pragma unroll
        for (int m = 0; m < 10; ++m) {
            unsigned wp = g_wf[0][o * 10 + m], wr = g_wf[1][o * 10 + m];
            acc0 += __popc(a0[m] & wp) - __popc(a0[m] & wr);
            acc1 += __popc(a1[m] & wp) - __popc(a1[m] & wr);
        }
        out[(size_t)(nb + 2 * pp + 0) * COUT + o] = (float)acc0 + bb;
        out[(size_t)(nb + 2 * pp + 1) * COUT + o] = (float)acc1 + bb;
    }
}

extern "C" void kernel_launch(void* const* d_in, const int* in_sizes, int n_in,
                              void* d_out, int out_size, void* d_ws, size_t ws_size,
                              hipStream_t stream) {
    const float* x    = (const float*)d_in[0];
    const float* pos  = (const float*)d_in[1];
    const int*   col  = (const int*)d_in[2];
    const float* W1   = (const float*)d_in[3];
    const float* b1   = (const float*)d_in[4];
    const float* bn1g = (const float*)d_in[5];
    const float* bn1b = (const float*)d_in[6];
    const float* bn1m = (const float*)d_in[7];
    const float* bn1v = (const float*)d_in[8];
    const float* W2   = (const float*)d_in[9];
    const float* b2   = (const float*)d_in[10];
    const float* bn2g = (const float*)d_in[11];
    const float* bn2b = (const float*)d_in[12];
    const float* bn2m = (const float*)d_in[13];
    const float* bn2v = (const float*)d_in[14];
    const float* Wm   = (const float*)d_in[15];
    const float* bm   = (const float*)d_in[16];
    const float* bn3g = (const float*)d_in[17];
    const float* bn3b = (const float*)d_in[18];
    const float* bn3m = (const float*)d_in[19];
    const float* bn3v = (const float*)d_in[20];
    const float* cw1  = (const float*)d_in[21];
    const float* cb1  = (const float*)d_in[22];
    const float* bn4g = (const float*)d_in[23];
    const float* bn4b = (const float*)d_in[24];
    const float* bn4m = (const float*)d_in[25];
    const float* bn4v = (const float*)d_in[26];
    const float* cw2  = (const float*)d_in[27];
    const float* cb2  = (const float*)d_in[28];
    const float* bn5g = (const float*)d_in[29];
    const float* bn5b = (const float*)d_in[30];
    const float* bn5m = (const float*)d_in[31];
    const float* bn5v = (const float*)d_in[32];
    const float* cw3  = (const float*)d_in[33];
    const float* cb3  = (const float*)d_in[34];
    const float* Wf   = (const float*)d_in[35];
    const float* bf   = (const float*)d_in[36];
    float* outp = (float*)d_out;

    hipLaunchKernelGGL(prep_kernel, dim3(52), dim3(256), 0, stream, Wm, W2, cw1, cw2, cw3, Wf);
    hipLaunchKernelGGL(bixconv_kernel, dim3(NPTS / PTS), dim3(256), 0, stream,
        x, pos, col,
        W1, b1, bn1g, bn1b, bn1m, bn1v,
        b2, bn2g, bn2b, bn2m, bn2v,
        bm, bn3g, bn3b, bn3m, bn3v,
        cb1, bn4g, bn4b, bn4m, bn4v,
        cb2, bn5g, bn5b, bn5m, bn5v,
        cb3, bf, outp);
}